// Round 14
// baseline (208.761 us; speedup 1.0000x reference)
//
#include <hip/hip_runtime.h>
#include <math.h>

typedef unsigned short u16;
typedef unsigned int u32;
typedef __attribute__((ext_vector_type(8))) short short8;
typedef __attribute__((ext_vector_type(4))) short short4v;
typedef __attribute__((ext_vector_type(4))) float f32x4;

// ---------- helpers ----------
__device__ __forceinline__ u16 f2bf(float f) {
  union { float f; unsigned u; } x; x.f = f;
  unsigned r = x.u + 0x7FFFu + ((x.u >> 16) & 1u);   // RNE
  return (u16)(r >> 16);
}

__device__ __forceinline__ u32 asu(float f) {
  union { float f; u32 u; } x; x.f = f; return x.u;
}

// pack two floats -> two bf16 (round-half-up) in one u32: lo=a, hi=b
__device__ __forceinline__ u32 pack2bf(float a, float b) {
  return __builtin_amdgcn_perm(asu(b) + 0x8000u, asu(a) + 0x8000u, 0x07060302u);
}

__device__ __forceinline__ void gld_lds16(const void* g, void* l) {
  __builtin_amdgcn_global_load_lds(
      (const __attribute__((address_space(1))) unsigned int*)g,
      (__attribute__((address_space(3))) unsigned int*)l, 16, 0, 0);
}

// ---------- fused preprocessing ----------
// cast Xq/Xc row-major bf16 + convert weights to FRAGMENT-MAJOR bf16.
// Chunk (n4=n>>4, k5=k>>5) at ((n4*32)+k5)*512; within chunk element (n,k):
// addr = (k>>3)*128 + (n&15)*8 + (k&7)  (verified R11).
__global__ void pre_kernel(const float* __restrict__ q, const float* __restrict__ c,
                           const float* __restrict__ Wq, const float* __restrict__ Wkv,
                           const float* __restrict__ Wo,
                           u16* __restrict__ xq, u16* __restrict__ xc,
                           u16* __restrict__ WqF, u16* __restrict__ WkvF,
                           u16* __restrict__ WoF) {
  __shared__ float tile[32][33];
  int bx = blockIdx.x;
  int t = threadIdx.y * 32 + threadIdx.x;
  if (bx < 8192) {
    int i = bx * 256 + t;
    const float* src = q; u16* dst = xq;
    if (i >= 1048576) { i -= 1048576; src = c; dst = xc; }
    float4 v = ((const float4*)src)[i];
    ((uint2*)dst)[i] = make_uint2(
        (unsigned)f2bf(v.x) | ((unsigned)f2bf(v.y) << 16),
        (unsigned)f2bf(v.z) | ((unsigned)f2bf(v.w) << 16));
  } else {
    int g = bx - 8192;
    int gx = g & 127, gy = g >> 7;               // gy = k-tile in [0,32)
    const float* src; u16* dst; int N, n0;
    if (gx < 32)      { src = Wq;  dst = WqF;  N = 1024; n0 = gx * 32; }
    else if (gx < 96) { src = Wkv; dst = WkvF; N = 2048; n0 = (gx - 32) * 32; }
    else              { src = Wo;  dst = WoF;  N = 1024; n0 = (gx - 96) * 32; }
    int k0 = gy * 32;
    int tx = threadIdx.x, ty = threadIdx.y;      // (32,8)
#pragma unroll
    for (int i = 0; i < 4; ++i)
      tile[ty * 4 + i][tx] = src[(size_t)(k0 + ty * 4 + i) * N + n0 + tx];
    __syncthreads();
    int e = t * 4;
    int ch = e >> 9, rem = e & 511;
    int kg = (rem >> 7) & 3;          // k-group of 8
    int nl = (rem >> 3) & 15;         // n within 16
    int j0 = rem & 7;                 // 0 or 4
    int kk = kg * 8 + j0;
    int nn = ch * 16 + nl;
    u32 lo = pack2bf(tile[kk][nn], tile[kk + 1][nn]);
    u32 hi = pack2bf(tile[kk + 2][nn], tile[kk + 3][nn]);
    *(uint2*)(dst + (size_t)(((n0 >> 4) + ch) * 32 + gy) * 512 + rem) = make_uint2(lo, hi);
  }
}

// ---------- fused QKV GEMM: 768 blocks (3/CU), 256 thr, 128x128 tiles ----------
// A staged via swizzled global_load_lds (R12); B-fragments direct from
// frag-major weights (L2-hit, no LDS).
__global__ __launch_bounds__(256) void qkv_gemm(
    const u16* __restrict__ Xq, const u16* __restrict__ Xc,
    const u16* __restrict__ WqF, const u16* __restrict__ WkvF,
    const float* __restrict__ bq, const float* __restrict__ bkv,
    u16* __restrict__ qb, u16* __restrict__ kf, u16* __restrict__ vf,
    float qscale) {
  __shared__ __align__(16) u16 smem[16896];      // As (16KB) / epilogue C-tile (33KB)
  u16* As = smem;
  const int tid = threadIdx.x, lane = tid & 63, wave = tid >> 6;
  const int quad = lane >> 4, cl = lane & 15;
  const int wr = (wave >> 1) * 64, wc = (wave & 1) * 64;

  int x = blockIdx.x;
  const u16 *A, *Bf; const float* bias; int m0, n0; bool isq;
  if (x < 256) {
    isq = true;  A = Xq; Bf = WqF;  bias = bq;
    m0 = (x >> 3) * 128; n0 = (x & 7) * 128;
  } else {
    isq = false; x -= 256; A = Xc; Bf = WkvF; bias = bkv;
    m0 = (x >> 4) * 128; n0 = (x & 15) * 128;
  }
  const int bn4 = (n0 + wc) >> 4;

  const int rA = lane >> 3;
  const int kcs = ((lane & 7) ^ rA) * 8;         // swizzled source k within 64
  const int r7 = cl & 7;                          // reader row&7

  f32x4 acc[4][4] = {};

  for (int k0 = 0; k0 < 1024; k0 += 64) {
#pragma unroll
    for (int it = 0; it < 4; ++it) {             // As: 16 chunks of 8 rows, 4/wave
      int chunk = it * 4 + wave;
      gld_lds16(A + (size_t)(m0 + chunk * 8 + rA) * 1024 + k0 + kcs, As + chunk * 512);
    }
    // B-fragments direct from global (no LDS dependency)
    short8 bf[2][4];
#pragma unroll
    for (int ks = 0; ks < 2; ++ks)
#pragma unroll
      for (int ni = 0; ni < 4; ++ni)
        bf[ks][ni] = *(const short8*)(Bf + (size_t)((bn4 + ni) * 32 + (k0 >> 5) + ks) * 512 + lane * 8);
    __syncthreads();
#pragma unroll
    for (int ks = 0; ks < 2; ++ks) {
      short8 af[4];
#pragma unroll
      for (int mi = 0; mi < 4; ++mi) {
        int row = wr + mi * 16 + cl;
        af[mi] = *(const short8*)(As + (row >> 3) * 512 + r7 * 64 +
                                  (((ks << 2) | quad) ^ r7) * 8);
      }
#pragma unroll
      for (int mi = 0; mi < 4; ++mi)
#pragma unroll
        for (int ni = 0; ni < 4; ++ni)
          acc[mi][ni] = __builtin_amdgcn_mfma_f32_16x16x32_bf16(af[mi], bf[ks][ni], acc[mi][ni], 0, 0, 0);
    }
    __syncthreads();
  }

  if (isq) {
#pragma unroll
    for (int mi = 0; mi < 4; ++mi)
#pragma unroll
      for (int ni = 0; ni < 4; ++ni)
#pragma unroll
        for (int r = 0; r < 4; ++r) {
          int row = m0 + wr + mi * 16 + quad * 4 + r;
          int col = n0 + wc + ni * 16 + cl;
          qb[(size_t)row * 1024 + col] = f2bf((acc[mi][ni][r] + bias[col]) * qscale);
        }
    return;
  }

  const int b = m0 >> 11, kt0 = (m0 & 2047) >> 6;
  const bool kreg = (n0 < 1024);
  if (kreg) {
    // K-tile -> LDS [t][d], stride 132 (scalar b16 stores; b128 frag reads)
#pragma unroll
    for (int mi = 0; mi < 4; ++mi)
#pragma unroll
      for (int ni = 0; ni < 4; ++ni)
#pragma unroll
        for (int r = 0; r < 4; ++r)
          smem[(wr + mi * 16 + quad * 4 + r) * 132 + wc + ni * 16 + cl] =
              f2bf(acc[mi][ni][r] + bias[n0 + wc + ni * 16 + cl]);
    __syncthreads();
#pragma unroll
    for (int i = 0; i < 8; ++i) {
      int c = i * 4 + wave;                       // 32 chunks
      int hs = c >> 4, ts = (c >> 3) & 1, ks = (c >> 2) & 1, idx = c & 3;
      int h = (n0 >> 6) + hs;
      size_t bhkt = ((size_t)((b * 16 + h) * 32 + kt0 + ts)) * 4096;
      short8 v = *(const short8*)(smem + (ts * 64 + idx * 16 + cl) * 132 +
                                  hs * 64 + ks * 32 + quad * 8);
      *(short8*)(kf + bhkt + (size_t)(ks * 4 + idx) * 512 + lane * 8) = v;
    }
  } else {
    // V-tile -> LDS transposed [d][t], stride 132, then emit relabeled V^T A-frags
#pragma unroll
    for (int mi = 0; mi < 4; ++mi)
#pragma unroll
      for (int ni = 0; ni < 4; ++ni) {
        float v0 = acc[mi][ni][0] + bias[n0 + wc + ni * 16 + cl];
        float v1 = acc[mi][ni][1] + bias[n0 + wc + ni * 16 + cl];
        float v2 = acc[mi][ni][2] + bias[n0 + wc + ni * 16 + cl];
        float v3 = acc[mi][ni][3] + bias[n0 + wc + ni * 16 + cl];
        *(uint2*)(smem + (wc + ni * 16 + cl) * 132 + wr + mi * 16 + quad * 4) =
            make_uint2(pack2bf(v0, v1), pack2bf(v2, v3));
      }
    __syncthreads();
#pragma unroll
    for (int i = 0; i < 8; ++i) {
      int c = i * 4 + wave;
      int hs = c >> 4, ts = (c >> 3) & 1, ks = (c >> 2) & 1, idx = c & 3;
      int h = ((n0 - 1024) >> 6) + hs;
      size_t bhkt = ((size_t)((b * 16 + h) * 32 + kt0 + ts)) * 4096;
      // k-slot j<4: t = ts*64 + ks*32 + quad*4 + j ; j>=4: +16
      const u16* src = smem + (hs * 64 + idx * 16 + cl) * 132 + ts * 64 + ks * 32 + quad * 4;
      short8 v;
      *(short4v*)&v       = *(const short4v*)(src);
      *((short4v*)&v + 1) = *(const short4v*)(src + 16);
      *(short8*)(vf + bhkt + (size_t)(ks * 4 + idx) * 512 + lane * 8) = v;
    }
  }
}

// ---------- O-proj: 256 blocks, 512 thr = 8 waves (2m x 4n, 64x32/wave) ----------
__global__ __launch_bounds__(512) void o_gemm(
    const u16* __restrict__ A, const u16* __restrict__ Bf,
    const float* __restrict__ bias, float* __restrict__ Cm) {
  __shared__ __align__(16) u16 As[128 * 64];
  const int tid = threadIdx.x, lane = tid & 63, wave = tid >> 6;
  const int quad = lane >> 4, cl = lane & 15;
  const int m0 = (blockIdx.x >> 3) * 128, n0 = (blockIdx.x & 7) * 128;
  const int wr = (wave >> 2) * 64, wc = (wave & 3) * 32;
  const int bn4 = (n0 + wc) >> 4;

  const int rA = lane >> 3;
  const int kcs = ((lane & 7) ^ rA) * 8;
  const int r7 = cl & 7;

  f32x4 acc[4][2] = {};

  for (int k0 = 0; k0 < 1024; k0 += 64) {
#pragma unroll
    for (int it = 0; it < 2; ++it) {
      int ch = it * 8 + wave;
      gld_lds16(A + (size_t)(m0 + ch * 8 + rA) * 1024 + k0 + kcs, As + ch * 512);
    }
    short8 bf[2][2];
#pragma unroll
    for (int ks = 0; ks < 2; ++ks)
#pragma unroll
      for (int ni = 0; ni < 2; ++ni)
        bf[ks][ni] = *(const short8*)(Bf + (size_t)((bn4 + ni) * 32 + (k0 >> 5) + ks) * 512 + lane * 8);
    __syncthreads();
#pragma unroll
    for (int ks = 0; ks < 2; ++ks) {
      short8 af[4];
#pragma unroll
      for (int mi = 0; mi < 4; ++mi) {
        int row = wr + mi * 16 + cl;
        af[mi] = *(const short8*)(As + (row >> 3) * 512 + r7 * 64 +
                                  (((ks << 2) | quad) ^ r7) * 8);
      }
#pragma unroll
      for (int mi = 0; mi < 4; ++mi)
#pragma unroll
        for (int ni = 0; ni < 2; ++ni)
          acc[mi][ni] = __builtin_amdgcn_mfma_f32_16x16x32_bf16(af[mi], bf[ks][ni], acc[mi][ni], 0, 0, 0);
    }
    __syncthreads();
  }
#pragma unroll
  for (int mi = 0; mi < 4; ++mi)
#pragma unroll
    for (int ni = 0; ni < 2; ++ni)
#pragma unroll
      for (int r = 0; r < 4; ++r) {
        int row = m0 + wr + mi * 16 + quad * 4 + r;
        int col = n0 + wc + ni * 16 + cl;
        Cm[(size_t)row * 1024 + col] = acc[mi][ni][r] + bias[col];
      }
}

// ---------- flash attention: 2-kt staging phases (half the barriers) ----------
// R13 evidence: ~half the kernel is barrier-drain stall (s_waitcnt vmcnt(0)
// before s_barrier drains the just-issued DMA every kt). Now each phase stages
// TWO kt tiles (32 KB) and has one barrier: drain frequency halved, in-flight
// time doubled (~1200 cyc compute cover). 32 Q-rows/wave, 512 blocks (2/CU,
// LDS 2x32KB=64KB -> fits 2 blocks/CU). Register-direct P, relabeled vf.
__global__ __launch_bounds__(256) void flash_attn(
    const u16* __restrict__ qb, const u16* __restrict__ kf,
    const u16* __restrict__ vf, u16* __restrict__ outp) {
  __shared__ __align__(16) u16 kv[2][32 * 512];  // [buf][2 kt x (K 0-7 | V 8-15)]
  const int tid = threadIdx.x, lane = tid & 63, wave = tid >> 6;
  const int quad = lane >> 4, cl = lane & 15;
  const int id = blockIdx.x;
  const int h = (id & 7) | (((id >> 3) & 1) << 3);   // XCD-aware: id%8 = h%8
  const int b = (id >> 4) & 1;
  const int qt = id >> 5;                            // [0,16): 128 Q rows/block

  const int qrow0 = b * 2048 + qt * 128 + wave * 32;
  short8 bq[2][2];   // [group][ks]: B[n=cl][k=quad*8+j], rows qrow0+g*16+cl
#pragma unroll
  for (int g = 0; g < 2; ++g)
#pragma unroll
    for (int ks = 0; ks < 2; ++ks)
      bq[g][ks] = *(const short8*)(qb + (size_t)(qrow0 + g * 16 + cl) * 1024 +
                                   h * 64 + ks * 32 + quad * 8);

  const u16* kfb = kf + (size_t)((b * 16 + h) * 32) * 4096;
  const u16* vfb = vf + (size_t)((b * 16 + h) * 32) * 4096;

  // stage phase p (kts 2p, 2p+1) into kv[buf]: 8 DMA instrs/wave
  auto stage = [&](int p, int buf) {
#pragma unroll
    for (int s = 0; s < 2; ++s) {
      int kt = p * 2 + s;
#pragma unroll
      for (int i = 0; i < 2; ++i) {
        int c = wave * 2 + i;
        gld_lds16(kfb + (size_t)kt * 4096 + c * 512 + lane * 8, &kv[buf][(s * 16 + c) * 512]);
        gld_lds16(vfb + (size_t)kt * 4096 + c * 512 + lane * 8, &kv[buf][(s * 16 + 8 + c) * 512]);
      }
    }
  };

  f32x4 o_acc[2][4] = {};   // [group] O^T: row d = nd*16+quad*4+r, col m = cl
  float l_lane[2] = {0.f, 0.f};

  stage(0, 0);
  __syncthreads();

#pragma unroll 1
  for (int p = 0; p < 16; ++p) {
    const int cur = p & 1, nxt = cur ^ 1;
    if (p < 15) stage(p + 1, nxt);             // 32 KB DMA; lands during this phase
#pragma unroll
    for (int s = 0; s < 2; ++s) {
      const u16* kb = &kv[cur][(s * 16) * 512];
      const u16* vb = &kv[cur][(s * 16 + 8) * 512];
      // S^T = K.Q^T : each K-frag read feeds both groups
      f32x4 st[2][4] = {};
#pragma unroll
      for (int ks = 0; ks < 2; ++ks)
#pragma unroll
        for (int ni = 0; ni < 4; ++ni) {
          short8 ak = *(const short8*)(kb + (ks * 4 + ni) * 512 + lane * 8);
          st[0][ni] = __builtin_amdgcn_mfma_f32_16x16x32_bf16(ak, bq[0][ks], st[0][ni], 0, 0, 0);
          st[1][ni] = __builtin_amdgcn_mfma_f32_16x16x32_bf16(ak, bq[1][ks], st[1][ni], 0, 0, 0);
        }
      // p = exp2(s), pack straight into PV B-fragments (register-direct)
      u32 bp[2][2][4];
#pragma unroll
      for (int g = 0; g < 2; ++g)
#pragma unroll
        for (int ni = 0; ni < 4; ++ni) {
          float p0 = __builtin_amdgcn_exp2f(st[g][ni][0]);
          float p1 = __builtin_amdgcn_exp2f(st[g][ni][1]);
          float p2 = __builtin_amdgcn_exp2f(st[g][ni][2]);
          float p3 = __builtin_amdgcn_exp2f(st[g][ni][3]);
          l_lane[g] += (p0 + p1) + (p2 + p3);
          bp[g][ni >> 1][(ni & 1) * 2 + 0] = pack2bf(p0, p1);
          bp[g][ni >> 1][(ni & 1) * 2 + 1] = pack2bf(p2, p3);
        }
      // O^T += V^T.P^T : each V-frag read feeds both groups
#pragma unroll
      for (int ks = 0; ks < 2; ++ks) {
        short8 pb0, pb1;
#pragma unroll
        for (int w = 0; w < 4; ++w) {
          ((u32*)&pb0)[w] = bp[0][ks][w];
          ((u32*)&pb1)[w] = bp[1][ks][w];
        }
#pragma unroll
        for (int nd = 0; nd < 4; ++nd) {
          short8 av = *(const short8*)(vb + (ks * 4 + nd) * 512 + lane * 8);
          o_acc[0][nd] = __builtin_amdgcn_mfma_f32_16x16x32_bf16(av, pb0, o_acc[0][nd], 0, 0, 0);
          o_acc[1][nd] = __builtin_amdgcn_mfma_f32_16x16x32_bf16(av, pb1, o_acc[1][nd], 0, 0, 0);
        }
      }
    }
    __syncthreads();   // waves done reading cur; DMA(nxt) drained (1 per 2 kt)
  }
  // epilogue per group: l row-sum, O^T -> O transpose via LDS, coalesced store
#pragma unroll
  for (int g = 0; g < 2; ++g) {
    float l = l_lane[g];
    l += __shfl_xor(l, 16);
    l += __shfl_xor(l, 32);
    float inv = 1.f / l;
    u16* Ow = &kv[0][(wave * 2 + g) * 16 * 68];
#pragma unroll
    for (int nd = 0; nd < 4; ++nd)
#pragma unroll
      for (int r2 = 0; r2 < 2; ++r2)
        *(u32*)(Ow + cl * 68 + nd * 16 + quad * 4 + r2 * 2) =
            pack2bf(o_acc[g][nd][r2 * 2] * inv, o_acc[g][nd][r2 * 2 + 1] * inv);
#pragma unroll
    for (int half = 0; half < 2; ++half) {
      int row = half * 8 + (lane >> 3);
      int d0 = (lane & 7) * 8;
      short8 ov = *(const short8*)(Ow + row * 68 + d0);
      *(short8*)(outp + (size_t)(qrow0 + g * 16 + row) * 1024 + h * 64 + d0) = ov;
    }
  }
}

// ---------- launch ----------
extern "C" void kernel_launch(void* const* d_in, const int* in_sizes, int n_in,
                              void* d_out, int out_size, void* d_ws, size_t ws_size,
                              hipStream_t stream) {
  const float* query   = (const float*)d_in[0];
  const float* context = (const float*)d_in[1];
  const float* Wq  = (const float*)d_in[2];
  const float* bq  = (const float*)d_in[3];
  const float* Wkv = (const float*)d_in[4];
  const float* bkv = (const float*)d_in[5];
  const float* Wo  = (const float*)d_in[6];
  const float* bo  = (const float*)d_in[7];
  float* out = (float*)d_out;

  char* ws = (char*)d_ws;
  size_t off = 0;
  auto alloc = [&](size_t bytes) {
    char* p = ws + off;
    off += (bytes + 255) & ~(size_t)255;
    return p;
  };
  u16* buf0 = (u16*)alloc(4096ull * 1024 * 2);   // Xq -> attn_out
  u16* xcb  = (u16*)alloc(4096ull * 1024 * 2);   // Xc
  u16* WqF  = (u16*)alloc(1024ull * 1024 * 2);   // frag-major weights
  u16* WkvF = (u16*)alloc(2048ull * 1024 * 2);
  u16* WoF  = (u16*)alloc(1024ull * 1024 * 2);
  u16* qb   = (u16*)alloc(4096ull * 1024 * 2);
  u16* kfr  = (u16*)alloc(4ull * 1024 * 1024 * 2);
  u16* vfr  = (u16*)alloc(4ull * 1024 * 1024 * 2);

  const float QSCALE = 0.125f * 1.44269504f;  // 1/sqrt(64) * log2(e)

  pre_kernel<<<12288, dim3(32, 8), 0, stream>>>(query, context, Wq, Wkv, Wo,
                                                buf0, xcb, WqF, WkvF, WoF);
  qkv_gemm<<<768, 256, 0, stream>>>(buf0, xcb, WqF, WkvF, bq, bkv,
                                    qb, kfr, vfr, QSCALE);
  flash_attn<<<512, 256, 0, stream>>>(qb, kfr, vfr, buf0);
  o_gemm<<<256, 512, 0, stream>>>(buf0, WoF, bo, out);
}

// Round 15
// 205.967 us; speedup vs baseline: 1.0136x; 1.0136x over previous
//
#include <hip/hip_runtime.h>
#include <math.h>

typedef unsigned short u16;
typedef unsigned int u32;
typedef __attribute__((ext_vector_type(8))) short short8;
typedef __attribute__((ext_vector_type(4))) short short4v;
typedef __attribute__((ext_vector_type(4))) float f32x4;

// ---------- helpers ----------
__device__ __forceinline__ u16 f2bf(float f) {
  union { float f; unsigned u; } x; x.f = f;
  unsigned r = x.u + 0x7FFFu + ((x.u >> 16) & 1u);   // RNE
  return (u16)(r >> 16);
}

__device__ __forceinline__ u32 asu(float f) {
  union { float f; u32 u; } x; x.f = f; return x.u;
}

// pack two floats -> two bf16 (round-half-up) in one u32: lo=a, hi=b
__device__ __forceinline__ u32 pack2bf(float a, float b) {
  return __builtin_amdgcn_perm(asu(b) + 0x8000u, asu(a) + 0x8000u, 0x07060302u);
}

__device__ __forceinline__ void gld_lds16(const void* g, void* l) {
  __builtin_amdgcn_global_load_lds(
      (const __attribute__((address_space(1))) unsigned int*)g,
      (__attribute__((address_space(3))) unsigned int*)l, 16, 0, 0);
}

// ---------- fused preprocessing ----------
// cast Xq/Xc row-major bf16 + convert weights to FRAGMENT-MAJOR bf16.
// Chunk (n4=n>>4, k5=k>>5) at ((n4*32)+k5)*512; within chunk element (n,k):
// addr = (k>>3)*128 + (n&15)*8 + (k&7)  (verified R11).
__global__ void pre_kernel(const float* __restrict__ q, const float* __restrict__ c,
                           const float* __restrict__ Wq, const float* __restrict__ Wkv,
                           const float* __restrict__ Wo,
                           u16* __restrict__ xq, u16* __restrict__ xc,
                           u16* __restrict__ WqF, u16* __restrict__ WkvF,
                           u16* __restrict__ WoF) {
  __shared__ float tile[32][33];
  int bx = blockIdx.x;
  int t = threadIdx.y * 32 + threadIdx.x;
  if (bx < 8192) {
    int i = bx * 256 + t;
    const float* src = q; u16* dst = xq;
    if (i >= 1048576) { i -= 1048576; src = c; dst = xc; }
    float4 v = ((const float4*)src)[i];
    ((uint2*)dst)[i] = make_uint2(
        (unsigned)f2bf(v.x) | ((unsigned)f2bf(v.y) << 16),
        (unsigned)f2bf(v.z) | ((unsigned)f2bf(v.w) << 16));
  } else {
    int g = bx - 8192;
    int gx = g & 127, gy = g >> 7;               // gy = k-tile in [0,32)
    const float* src; u16* dst; int N, n0;
    if (gx < 32)      { src = Wq;  dst = WqF;  N = 1024; n0 = gx * 32; }
    else if (gx < 96) { src = Wkv; dst = WkvF; N = 2048; n0 = (gx - 32) * 32; }
    else              { src = Wo;  dst = WoF;  N = 1024; n0 = (gx - 96) * 32; }
    int k0 = gy * 32;
    int tx = threadIdx.x, ty = threadIdx.y;      // (32,8)
#pragma unroll
    for (int i = 0; i < 4; ++i)
      tile[ty * 4 + i][tx] = src[(size_t)(k0 + ty * 4 + i) * N + n0 + tx];
    __syncthreads();
    int e = t * 4;
    int ch = e >> 9, rem = e & 511;
    int kg = (rem >> 7) & 3;          // k-group of 8
    int nl = (rem >> 3) & 15;         // n within 16
    int j0 = rem & 7;                 // 0 or 4
    int kk = kg * 8 + j0;
    int nn = ch * 16 + nl;
    u32 lo = pack2bf(tile[kk][nn], tile[kk + 1][nn]);
    u32 hi = pack2bf(tile[kk + 2][nn], tile[kk + 3][nn]);
    *(uint2*)(dst + (size_t)(((n0 >> 4) + ch) * 32 + gy) * 512 + rem) = make_uint2(lo, hi);
  }
}

// ---------- fused QKV GEMM: 768 blocks (3/CU), 256 thr, 128x128 tiles ----------
// A staged via swizzled global_load_lds (R12); B-fragments direct from
// frag-major weights (L2-hit, no LDS).
__global__ __launch_bounds__(256) void qkv_gemm(
    const u16* __restrict__ Xq, const u16* __restrict__ Xc,
    const u16* __restrict__ WqF, const u16* __restrict__ WkvF,
    const float* __restrict__ bq, const float* __restrict__ bkv,
    u16* __restrict__ qb, u16* __restrict__ kf, u16* __restrict__ vf,
    float qscale) {
  __shared__ __align__(16) u16 smem[16896];      // As (16KB) / epilogue C-tile (33KB)
  u16* As = smem;
  const int tid = threadIdx.x, lane = tid & 63, wave = tid >> 6;
  const int quad = lane >> 4, cl = lane & 15;
  const int wr = (wave >> 1) * 64, wc = (wave & 1) * 64;

  int x = blockIdx.x;
  const u16 *A, *Bf; const float* bias; int m0, n0; bool isq;
  if (x < 256) {
    isq = true;  A = Xq; Bf = WqF;  bias = bq;
    m0 = (x >> 3) * 128; n0 = (x & 7) * 128;
  } else {
    isq = false; x -= 256; A = Xc; Bf = WkvF; bias = bkv;
    m0 = (x >> 4) * 128; n0 = (x & 15) * 128;
  }
  const int bn4 = (n0 + wc) >> 4;

  const int rA = lane >> 3;
  const int kcs = ((lane & 7) ^ rA) * 8;         // swizzled source k within 64
  const int r7 = cl & 7;                          // reader row&7

  f32x4 acc[4][4] = {};

  for (int k0 = 0; k0 < 1024; k0 += 64) {
#pragma unroll
    for (int it = 0; it < 4; ++it) {             // As: 16 chunks of 8 rows, 4/wave
      int chunk = it * 4 + wave;
      gld_lds16(A + (size_t)(m0 + chunk * 8 + rA) * 1024 + k0 + kcs, As + chunk * 512);
    }
    // B-fragments direct from global (no LDS dependency)
    short8 bf[2][4];
#pragma unroll
    for (int ks = 0; ks < 2; ++ks)
#pragma unroll
      for (int ni = 0; ni < 4; ++ni)
        bf[ks][ni] = *(const short8*)(Bf + (size_t)((bn4 + ni) * 32 + (k0 >> 5) + ks) * 512 + lane * 8);
    __syncthreads();
#pragma unroll
    for (int ks = 0; ks < 2; ++ks) {
      short8 af[4];
#pragma unroll
      for (int mi = 0; mi < 4; ++mi) {
        int row = wr + mi * 16 + cl;
        af[mi] = *(const short8*)(As + (row >> 3) * 512 + r7 * 64 +
                                  (((ks << 2) | quad) ^ r7) * 8);
      }
#pragma unroll
      for (int mi = 0; mi < 4; ++mi)
#pragma unroll
        for (int ni = 0; ni < 4; ++ni)
          acc[mi][ni] = __builtin_amdgcn_mfma_f32_16x16x32_bf16(af[mi], bf[ks][ni], acc[mi][ni], 0, 0, 0);
    }
    __syncthreads();
  }

  if (isq) {
#pragma unroll
    for (int mi = 0; mi < 4; ++mi)
#pragma unroll
      for (int ni = 0; ni < 4; ++ni)
#pragma unroll
        for (int r = 0; r < 4; ++r) {
          int row = m0 + wr + mi * 16 + quad * 4 + r;
          int col = n0 + wc + ni * 16 + cl;
          qb[(size_t)row * 1024 + col] = f2bf((acc[mi][ni][r] + bias[col]) * qscale);
        }
    return;
  }

  const int b = m0 >> 11, kt0 = (m0 & 2047) >> 6;
  const bool kreg = (n0 < 1024);
  if (kreg) {
    // K-tile -> LDS [t][d], stride 132 (scalar b16 stores; b128 frag reads)
#pragma unroll
    for (int mi = 0; mi < 4; ++mi)
#pragma unroll
      for (int ni = 0; ni < 4; ++ni)
#pragma unroll
        for (int r = 0; r < 4; ++r)
          smem[(wr + mi * 16 + quad * 4 + r) * 132 + wc + ni * 16 + cl] =
              f2bf(acc[mi][ni][r] + bias[n0 + wc + ni * 16 + cl]);
    __syncthreads();
#pragma unroll
    for (int i = 0; i < 8; ++i) {
      int c = i * 4 + wave;                       // 32 chunks
      int hs = c >> 4, ts = (c >> 3) & 1, ks = (c >> 2) & 1, idx = c & 3;
      int h = (n0 >> 6) + hs;
      size_t bhkt = ((size_t)((b * 16 + h) * 32 + kt0 + ts)) * 4096;
      short8 v = *(const short8*)(smem + (ts * 64 + idx * 16 + cl) * 132 +
                                  hs * 64 + ks * 32 + quad * 8);
      *(short8*)(kf + bhkt + (size_t)(ks * 4 + idx) * 512 + lane * 8) = v;
    }
  } else {
    // V-tile -> LDS transposed [d][t], stride 132, then emit relabeled V^T A-frags
#pragma unroll
    for (int mi = 0; mi < 4; ++mi)
#pragma unroll
      for (int ni = 0; ni < 4; ++ni) {
        float v0 = acc[mi][ni][0] + bias[n0 + wc + ni * 16 + cl];
        float v1 = acc[mi][ni][1] + bias[n0 + wc + ni * 16 + cl];
        float v2 = acc[mi][ni][2] + bias[n0 + wc + ni * 16 + cl];
        float v3 = acc[mi][ni][3] + bias[n0 + wc + ni * 16 + cl];
        *(uint2*)(smem + (wc + ni * 16 + cl) * 132 + wr + mi * 16 + quad * 4) =
            make_uint2(pack2bf(v0, v1), pack2bf(v2, v3));
      }
    __syncthreads();
#pragma unroll
    for (int i = 0; i < 8; ++i) {
      int c = i * 4 + wave;
      int hs = c >> 4, ts = (c >> 3) & 1, ks = (c >> 2) & 1, idx = c & 3;
      int h = ((n0 - 1024) >> 6) + hs;
      size_t bhkt = ((size_t)((b * 16 + h) * 32 + kt0 + ts)) * 4096;
      // k-slot j<4: t = ts*64 + ks*32 + quad*4 + j ; j>=4: +16
      const u16* src = smem + (hs * 64 + idx * 16 + cl) * 132 + ts * 64 + ks * 32 + quad * 4;
      short8 v;
      *(short4v*)&v       = *(const short4v*)(src);
      *((short4v*)&v + 1) = *(const short4v*)(src + 16);
      *(short8*)(vf + bhkt + (size_t)(ks * 4 + idx) * 512 + lane * 8) = v;
    }
  }
}

// ---------- O-proj: 512 blocks (2/CU), 256 thr, 64x128 tiles ----------
// qkv-mirror density: 2x2 waves of 32x64 -> 16 MFMA : 4 ds_read per iter
// (2x qkv's MFMA:LDS ratio). Swizzled A-DMA + direct-B frag loads.
// (Old config: 256 blocks/512thr = 1 block/CU, 1 wave/SIMD, 8 MFMA/barrier.)
__global__ __launch_bounds__(256) void o_gemm(
    const u16* __restrict__ A, const u16* __restrict__ Bf,
    const float* __restrict__ bias, float* __restrict__ Cm) {
  __shared__ __align__(16) u16 As[64 * 64];      // 8 chunks of 512
  const int tid = threadIdx.x, lane = tid & 63, wave = tid >> 6;
  const int quad = lane >> 4, cl = lane & 15;
  const int m0 = (blockIdx.x >> 3) * 64, n0 = (blockIdx.x & 7) * 128;
  const int wr = (wave >> 1) * 32, wc = (wave & 1) * 64;
  const int bn4 = (n0 + wc) >> 4;

  const int rA = lane >> 3;
  const int kcs = ((lane & 7) ^ rA) * 8;
  const int r7 = cl & 7;

  f32x4 acc[2][4] = {};

  for (int k0 = 0; k0 < 1024; k0 += 64) {
#pragma unroll
    for (int it = 0; it < 2; ++it) {             // As: 8 chunks of 8 rows, 2/wave
      int chunk = wave * 2 + it;
      gld_lds16(A + (size_t)(m0 + chunk * 8 + rA) * 1024 + k0 + kcs, As + chunk * 512);
    }
    short8 bf[2][4];
#pragma unroll
    for (int ks = 0; ks < 2; ++ks)
#pragma unroll
      for (int ni = 0; ni < 4; ++ni)
        bf[ks][ni] = *(const short8*)(Bf + (size_t)((bn4 + ni) * 32 + (k0 >> 5) + ks) * 512 + lane * 8);
    __syncthreads();
#pragma unroll
    for (int ks = 0; ks < 2; ++ks) {
      short8 af[2];
#pragma unroll
      for (int mi = 0; mi < 2; ++mi) {
        int row = wr + mi * 16 + cl;
        af[mi] = *(const short8*)(As + (row >> 3) * 512 + r7 * 64 +
                                  (((ks << 2) | quad) ^ r7) * 8);
      }
#pragma unroll
      for (int mi = 0; mi < 2; ++mi)
#pragma unroll
        for (int ni = 0; ni < 4; ++ni)
          acc[mi][ni] = __builtin_amdgcn_mfma_f32_16x16x32_bf16(af[mi], bf[ks][ni], acc[mi][ni], 0, 0, 0);
    }
    __syncthreads();
  }
#pragma unroll
  for (int mi = 0; mi < 2; ++mi)
#pragma unroll
    for (int ni = 0; ni < 4; ++ni)
#pragma unroll
      for (int r = 0; r < 4; ++r) {
        int row = m0 + wr + mi * 16 + quad * 4 + r;
        int col = n0 + wc + ni * 16 + cl;
        Cm[(size_t)row * 1024 + col] = acc[mi][ni][r] + bias[col];
      }
}

// ---------- flash attention: R12 exact (best measured: 49.4 us) ----------
__global__ __launch_bounds__(256, 4) void flash_attn(
    const u16* __restrict__ qb, const u16* __restrict__ kf,
    const u16* __restrict__ vf, u16* __restrict__ outp) {
  __shared__ __align__(16) u16 kv[2][16 * 512];    // [buf][K chunks 0-7 | V chunks 8-15]
  const int tid = threadIdx.x, lane = tid & 63, wave = tid >> 6;
  const int quad = lane >> 4, cl = lane & 15;
  const int id = blockIdx.x;
  const int h = (id & 7) | (((id >> 3) & 1) << 3);   // XCD-aware: id%8 = h%8
  const int b = (id >> 4) & 1;
  const int qt = id >> 5;

  const int qrow0 = b * 2048 + qt * 64 + wave * 16;
  short8 bq[2];   // Q as B-operand: B[n=cl][k=quad*8+j]
#pragma unroll
  for (int ks = 0; ks < 2; ++ks)
    bq[ks] = *(const short8*)(qb + (size_t)(qrow0 + cl) * 1024 + h * 64 + ks * 32 + quad * 8);

  const u16* kfb = kf + (size_t)((b * 16 + h) * 32) * 4096;
  const u16* vfb = vf + (size_t)((b * 16 + h) * 32) * 4096;

  auto stage = [&](int kt, int buf) {
#pragma unroll
    for (int i = 0; i < 2; ++i) {
      int c = wave * 2 + i;
      gld_lds16(kfb + (size_t)kt * 4096 + c * 512 + lane * 8, &kv[buf][c * 512]);
      gld_lds16(vfb + (size_t)kt * 4096 + c * 512 + lane * 8, &kv[buf][(8 + c) * 512]);
    }
  };

  f32x4 o_acc[4] = {};   // O^T: row d = nd*16+quad*4+r, col m = cl
  float l_lane = 0.f;

  stage(0, 0);
  __syncthreads();

#pragma unroll 1
  for (int kt = 0; kt < 32; ++kt) {
    const int cur = kt & 1, nxt = cur ^ 1;
    if (kt < 31) stage(kt + 1, nxt);           // DMA overlaps this iter's compute
    const u16* kb = &kv[cur][0];
    const u16* vb = &kv[cur][8 * 512];
    f32x4 st[4] = {};
#pragma unroll
    for (int ks = 0; ks < 2; ++ks)
#pragma unroll
      for (int ni = 0; ni < 4; ++ni) {
        short8 ak = *(const short8*)(kb + (ks * 4 + ni) * 512 + lane * 8);
        st[ni] = __builtin_amdgcn_mfma_f32_16x16x32_bf16(ak, bq[ks], st[ni], 0, 0, 0);
      }
    u32 bp[2][4];
#pragma unroll
    for (int ni = 0; ni < 4; ++ni) {
      float p0 = __builtin_amdgcn_exp2f(st[ni][0]);
      float p1 = __builtin_amdgcn_exp2f(st[ni][1]);
      float p2 = __builtin_amdgcn_exp2f(st[ni][2]);
      float p3 = __builtin_amdgcn_exp2f(st[ni][3]);
      l_lane += (p0 + p1) + (p2 + p3);
      bp[ni >> 1][(ni & 1) * 2 + 0] = pack2bf(p0, p1);
      bp[ni >> 1][(ni & 1) * 2 + 1] = pack2bf(p2, p3);
    }
#pragma unroll
    for (int ks = 0; ks < 2; ++ks) {
      short8 pb;
      *(u32*)&pb     = bp[ks][0];
      ((u32*)&pb)[1] = bp[ks][1];
      ((u32*)&pb)[2] = bp[ks][2];
      ((u32*)&pb)[3] = bp[ks][3];
#pragma unroll
      for (int nd = 0; nd < 4; ++nd) {
        short8 av = *(const short8*)(vb + (ks * 4 + nd) * 512 + lane * 8);
        o_acc[nd] = __builtin_amdgcn_mfma_f32_16x16x32_bf16(av, pb, o_acc[nd], 0, 0, 0);
      }
    }
    __syncthreads();   // waves done reading cur; DMA(nxt) drained
  }
  l_lane += __shfl_xor(l_lane, 16);
  l_lane += __shfl_xor(l_lane, 32);
  float inv = 1.f / l_lane;
  u16* Ow = &kv[0][wave * 16 * 68];
#pragma unroll
  for (int nd = 0; nd < 4; ++nd)
#pragma unroll
    for (int r2 = 0; r2 < 2; ++r2)
      *(u32*)(Ow + cl * 68 + nd * 16 + quad * 4 + r2 * 2) =
          pack2bf(o_acc[nd][r2 * 2] * inv, o_acc[nd][r2 * 2 + 1] * inv);
#pragma unroll
  for (int half = 0; half < 2; ++half) {
    int row = half * 8 + (lane >> 3);
    int d0 = (lane & 7) * 8;
    short8 ov = *(const short8*)(Ow + row * 68 + d0);
    *(short8*)(outp + (size_t)(qrow0 + row) * 1024 + h * 64 + d0) = ov;
  }
}

// ---------- launch ----------
extern "C" void kernel_launch(void* const* d_in, const int* in_sizes, int n_in,
                              void* d_out, int out_size, void* d_ws, size_t ws_size,
                              hipStream_t stream) {
  const float* query   = (const float*)d_in[0];
  const float* context = (const float*)d_in[1];
  const float* Wq  = (const float*)d_in[2];
  const float* bq  = (const float*)d_in[3];
  const float* Wkv = (const float*)d_in[4];
  const float* bkv = (const float*)d_in[5];
  const float* Wo  = (const float*)d_in[6];
  const float* bo  = (const float*)d_in[7];
  float* out = (float*)d_out;

  char* ws = (char*)d_ws;
  size_t off = 0;
  auto alloc = [&](size_t bytes) {
    char* p = ws + off;
    off += (bytes + 255) & ~(size_t)255;
    return p;
  };
  u16* buf0 = (u16*)alloc(4096ull * 1024 * 2);   // Xq -> attn_out
  u16* xcb  = (u16*)alloc(4096ull * 1024 * 2);   // Xc
  u16* WqF  = (u16*)alloc(1024ull * 1024 * 2);   // frag-major weights
  u16* WkvF = (u16*)alloc(2048ull * 1024 * 2);
  u16* WoF  = (u16*)alloc(1024ull * 1024 * 2);
  u16* qb   = (u16*)alloc(4096ull * 1024 * 2);
  u16* kfr  = (u16*)alloc(4ull * 1024 * 1024 * 2);
  u16* vfr  = (u16*)alloc(4ull * 1024 * 1024 * 2);

  const float QSCALE = 0.125f * 1.44269504f;  // 1/sqrt(64) * log2(e)

  pre_kernel<<<12288, dim3(32, 8), 0, stream>>>(query, context, Wq, Wkv, Wo,
                                                buf0, xcb, WqF, WkvF, WoF);
  qkv_gemm<<<768, 256, 0, stream>>>(buf0, xcb, WqF, WkvF, bq, bkv,
                                    qb, kfr, vfr, QSCALE);
  flash_attn<<<1024, 256, 0, stream>>>(qb, kfr, vfr, buf0);
  o_gemm<<<512, 256, 0, stream>>>(buf0, WoF, bo, out);
}

// Round 16
// 201.476 us; speedup vs baseline: 1.0362x; 1.0223x over previous
//
#include <hip/hip_runtime.h>
#include <math.h>

typedef unsigned short u16;
typedef unsigned int u32;
typedef __attribute__((ext_vector_type(8))) short short8;
typedef __attribute__((ext_vector_type(4))) short short4v;
typedef __attribute__((ext_vector_type(4))) float f32x4;

// ---------- helpers ----------
__device__ __forceinline__ u16 f2bf(float f) {
  union { float f; unsigned u; } x; x.f = f;
  unsigned r = x.u + 0x7FFFu + ((x.u >> 16) & 1u);   // RNE
  return (u16)(r >> 16);
}

__device__ __forceinline__ u32 asu(float f) {
  union { float f; u32 u; } x; x.f = f; return x.u;
}

// pack two floats -> two bf16 (round-half-up) in one u32: lo=a, hi=b
__device__ __forceinline__ u32 pack2bf(float a, float b) {
  return __builtin_amdgcn_perm(asu(b) + 0x8000u, asu(a) + 0x8000u, 0x07060302u);
}

__device__ __forceinline__ void gld_lds16(const void* g, void* l) {
  __builtin_amdgcn_global_load_lds(
      (const __attribute__((address_space(1))) unsigned int*)g,
      (__attribute__((address_space(3))) unsigned int*)l, 16, 0, 0);
}

// ---------- fused preprocessing ----------
// cast Xq/Xc row-major bf16 + convert weights to FRAGMENT-MAJOR bf16.
// Chunk (n4=n>>4, k5=k>>5) at ((n4*32)+k5)*512; within chunk element (n,k):
// addr = (k>>3)*128 + (n&15)*8 + (k&7)  (verified R11).
__global__ void pre_kernel(const float* __restrict__ q, const float* __restrict__ c,
                           const float* __restrict__ Wq, const float* __restrict__ Wkv,
                           const float* __restrict__ Wo,
                           u16* __restrict__ xq, u16* __restrict__ xc,
                           u16* __restrict__ WqF, u16* __restrict__ WkvF,
                           u16* __restrict__ WoF) {
  __shared__ float tile[32][33];
  int bx = blockIdx.x;
  int t = threadIdx.y * 32 + threadIdx.x;
  if (bx < 8192) {
    int i = bx * 256 + t;
    const float* src = q; u16* dst = xq;
    if (i >= 1048576) { i -= 1048576; src = c; dst = xc; }
    float4 v = ((const float4*)src)[i];
    ((uint2*)dst)[i] = make_uint2(
        (unsigned)f2bf(v.x) | ((unsigned)f2bf(v.y) << 16),
        (unsigned)f2bf(v.z) | ((unsigned)f2bf(v.w) << 16));
  } else {
    int g = bx - 8192;
    int gx = g & 127, gy = g >> 7;               // gy = k-tile in [0,32)
    const float* src; u16* dst; int N, n0;
    if (gx < 32)      { src = Wq;  dst = WqF;  N = 1024; n0 = gx * 32; }
    else if (gx < 96) { src = Wkv; dst = WkvF; N = 2048; n0 = (gx - 32) * 32; }
    else              { src = Wo;  dst = WoF;  N = 1024; n0 = (gx - 96) * 32; }
    int k0 = gy * 32;
    int tx = threadIdx.x, ty = threadIdx.y;      // (32,8)
#pragma unroll
    for (int i = 0; i < 4; ++i)
      tile[ty * 4 + i][tx] = src[(size_t)(k0 + ty * 4 + i) * N + n0 + tx];
    __syncthreads();
    int e = t * 4;
    int ch = e >> 9, rem = e & 511;
    int kg = (rem >> 7) & 3;          // k-group of 8
    int nl = (rem >> 3) & 15;         // n within 16
    int j0 = rem & 7;                 // 0 or 4
    int kk = kg * 8 + j0;
    int nn = ch * 16 + nl;
    u32 lo = pack2bf(tile[kk][nn], tile[kk + 1][nn]);
    u32 hi = pack2bf(tile[kk + 2][nn], tile[kk + 3][nn]);
    *(uint2*)(dst + (size_t)(((n0 >> 4) + ch) * 32 + gy) * 512 + rem) = make_uint2(lo, hi);
  }
}

// ---------- fused QKV GEMM: 768 blocks (3/CU), 256 thr, 128x128 tiles ----------
// A staged via swizzled global_load_lds into DOUBLE-BUFFERED LDS (2x16KB):
// stage(k+1) issues at iter top, full compute phase in flight before the
// barrier drain -> ONE barrier/iter (was: DMA-issue -> immediate barrier =
// uncovered vmcnt(0) drain every iter). B-frags direct from frag-major
// weights (L2-hit, no LDS).
__global__ __launch_bounds__(256) void qkv_gemm(
    const u16* __restrict__ Xq, const u16* __restrict__ Xc,
    const u16* __restrict__ WqF, const u16* __restrict__ WkvF,
    const float* __restrict__ bq, const float* __restrict__ bkv,
    u16* __restrict__ qb, u16* __restrict__ kf, u16* __restrict__ vf,
    float qscale) {
  __shared__ __align__(16) u16 smem[16896];      // K-loop: As dbuf 2x8192 / epilogue: C-tile
  const int tid = threadIdx.x, lane = tid & 63, wave = tid >> 6;
  const int quad = lane >> 4, cl = lane & 15;
  const int wr = (wave >> 1) * 64, wc = (wave & 1) * 64;

  int x = blockIdx.x;
  const u16 *A, *Bf; const float* bias; int m0, n0; bool isq;
  if (x < 256) {
    isq = true;  A = Xq; Bf = WqF;  bias = bq;
    m0 = (x >> 3) * 128; n0 = (x & 7) * 128;
  } else {
    isq = false; x -= 256; A = Xc; Bf = WkvF; bias = bkv;
    m0 = (x >> 4) * 128; n0 = (x & 15) * 128;
  }
  const int bn4 = (n0 + wc) >> 4;

  const int rA = lane >> 3;
  const int kcs = ((lane & 7) ^ rA) * 8;         // swizzled source k within 64
  const int r7 = cl & 7;                          // reader row&7

  // stage BK=64 A-tile for k0 into buffer buf (16 chunks, 4/wave)
  auto stageA = [&](int k0, int buf) {
    u16* As = smem + buf * 8192;
#pragma unroll
    for (int it = 0; it < 4; ++it) {
      int chunk = it * 4 + wave;
      gld_lds16(A + (size_t)(m0 + chunk * 8 + rA) * 1024 + k0 + kcs, As + chunk * 512);
    }
  };

  f32x4 acc[4][4] = {};

  stageA(0, 0);
  __syncthreads();                               // drain stage0 (only uncovered drain)

  for (int i = 0; i < 16; ++i) {
    const int k0 = i * 64;
    const int cur = i & 1;
    if (i < 15) stageA(k0 + 64, cur ^ 1);        // DMA in flight through compute below
    const u16* As = smem + cur * 8192;
    short8 bf[2][4];
#pragma unroll
    for (int ks = 0; ks < 2; ++ks)
#pragma unroll
      for (int ni = 0; ni < 4; ++ni)
        bf[ks][ni] = *(const short8*)(Bf + (size_t)((bn4 + ni) * 32 + (k0 >> 5) + ks) * 512 + lane * 8);
#pragma unroll
    for (int ks = 0; ks < 2; ++ks) {
      short8 af[4];
#pragma unroll
      for (int mi = 0; mi < 4; ++mi) {
        int row = wr + mi * 16 + cl;
        af[mi] = *(const short8*)(As + (row >> 3) * 512 + r7 * 64 +
                                  (((ks << 2) | quad) ^ r7) * 8);
      }
#pragma unroll
      for (int mi = 0; mi < 4; ++mi)
#pragma unroll
        for (int ni = 0; ni < 4; ++ni)
          acc[mi][ni] = __builtin_amdgcn_mfma_f32_16x16x32_bf16(af[mi], bf[ks][ni], acc[mi][ni], 0, 0, 0);
    }
    __syncthreads();   // reads of cur done (safe to overwrite next iter); DMA(nxt) drained
  }

  if (isq) {
#pragma unroll
    for (int mi = 0; mi < 4; ++mi)
#pragma unroll
      for (int ni = 0; ni < 4; ++ni)
#pragma unroll
        for (int r = 0; r < 4; ++r) {
          int row = m0 + wr + mi * 16 + quad * 4 + r;
          int col = n0 + wc + ni * 16 + cl;
          qb[(size_t)row * 1024 + col] = f2bf((acc[mi][ni][r] + bias[col]) * qscale);
        }
    return;
  }

  const int b = m0 >> 11, kt0 = (m0 & 2047) >> 6;
  const bool kreg = (n0 < 1024);
  if (kreg) {
    // K-tile -> LDS [t][d], stride 132 (scalar b16 stores; b128 frag reads)
#pragma unroll
    for (int mi = 0; mi < 4; ++mi)
#pragma unroll
      for (int ni = 0; ni < 4; ++ni)
#pragma unroll
        for (int r = 0; r < 4; ++r)
          smem[(wr + mi * 16 + quad * 4 + r) * 132 + wc + ni * 16 + cl] =
              f2bf(acc[mi][ni][r] + bias[n0 + wc + ni * 16 + cl]);
    __syncthreads();
#pragma unroll
    for (int i = 0; i < 8; ++i) {
      int c = i * 4 + wave;                       // 32 chunks
      int hs = c >> 4, ts = (c >> 3) & 1, ks = (c >> 2) & 1, idx = c & 3;
      int h = (n0 >> 6) + hs;
      size_t bhkt = ((size_t)((b * 16 + h) * 32 + kt0 + ts)) * 4096;
      short8 v = *(const short8*)(smem + (ts * 64 + idx * 16 + cl) * 132 +
                                  hs * 64 + ks * 32 + quad * 8);
      *(short8*)(kf + bhkt + (size_t)(ks * 4 + idx) * 512 + lane * 8) = v;
    }
  } else {
    // V-tile -> LDS transposed [d][t], stride 132, then emit relabeled V^T A-frags
#pragma unroll
    for (int mi = 0; mi < 4; ++mi)
#pragma unroll
      for (int ni = 0; ni < 4; ++ni) {
        float v0 = acc[mi][ni][0] + bias[n0 + wc + ni * 16 + cl];
        float v1 = acc[mi][ni][1] + bias[n0 + wc + ni * 16 + cl];
        float v2 = acc[mi][ni][2] + bias[n0 + wc + ni * 16 + cl];
        float v3 = acc[mi][ni][3] + bias[n0 + wc + ni * 16 + cl];
        *(uint2*)(smem + (wc + ni * 16 + cl) * 132 + wr + mi * 16 + quad * 4) =
            make_uint2(pack2bf(v0, v1), pack2bf(v2, v3));
      }
    __syncthreads();
#pragma unroll
    for (int i = 0; i < 8; ++i) {
      int c = i * 4 + wave;
      int hs = c >> 4, ts = (c >> 3) & 1, ks = (c >> 2) & 1, idx = c & 3;
      int h = ((n0 - 1024) >> 6) + hs;
      size_t bhkt = ((size_t)((b * 16 + h) * 32 + kt0 + ts)) * 4096;
      // k-slot j<4: t = ts*64 + ks*32 + quad*4 + j ; j>=4: +16
      const u16* src = smem + (hs * 64 + idx * 16 + cl) * 132 + ts * 64 + ks * 32 + quad * 4;
      short8 v;
      *(short4v*)&v       = *(const short4v*)(src);
      *((short4v*)&v + 1) = *(const short4v*)(src + 16);
      *(short8*)(vf + bhkt + (size_t)(ks * 4 + idx) * 512 + lane * 8) = v;
    }
  }
}

// ---------- O-proj: 512 blocks (2/CU), 256 thr, 64x128 tiles ----------
// Same dbuf single-barrier structure as qkv (As dbuf 2x8KB).
__global__ __launch_bounds__(256) void o_gemm(
    const u16* __restrict__ A, const u16* __restrict__ Bf,
    const float* __restrict__ bias, float* __restrict__ Cm) {
  __shared__ __align__(16) u16 As[2][64 * 64];   // dbuf, 8 chunks each
  const int tid = threadIdx.x, lane = tid & 63, wave = tid >> 6;
  const int quad = lane >> 4, cl = lane & 15;
  const int m0 = (blockIdx.x >> 3) * 64, n0 = (blockIdx.x & 7) * 128;
  const int wr = (wave >> 1) * 32, wc = (wave & 1) * 64;
  const int bn4 = (n0 + wc) >> 4;

  const int rA = lane >> 3;
  const int kcs = ((lane & 7) ^ rA) * 8;
  const int r7 = cl & 7;

  auto stageA = [&](int k0, int buf) {
#pragma unroll
    for (int it = 0; it < 2; ++it) {
      int chunk = wave * 2 + it;
      gld_lds16(A + (size_t)(m0 + chunk * 8 + rA) * 1024 + k0 + kcs, As[buf] + chunk * 512);
    }
  };

  f32x4 acc[2][4] = {};

  stageA(0, 0);
  __syncthreads();

  for (int i = 0; i < 16; ++i) {
    const int k0 = i * 64;
    const int cur = i & 1;
    if (i < 15) stageA(k0 + 64, cur ^ 1);
    short8 bf[2][4];
#pragma unroll
    for (int ks = 0; ks < 2; ++ks)
#pragma unroll
      for (int ni = 0; ni < 4; ++ni)
        bf[ks][ni] = *(const short8*)(Bf + (size_t)((bn4 + ni) * 32 + (k0 >> 5) + ks) * 512 + lane * 8);
#pragma unroll
    for (int ks = 0; ks < 2; ++ks) {
      short8 af[2];
#pragma unroll
      for (int mi = 0; mi < 2; ++mi) {
        int row = wr + mi * 16 + cl;
        af[mi] = *(const short8*)(As[cur] + (row >> 3) * 512 + r7 * 64 +
                                  (((ks << 2) | quad) ^ r7) * 8);
      }
#pragma unroll
      for (int mi = 0; mi < 2; ++mi)
#pragma unroll
        for (int ni = 0; ni < 4; ++ni)
          acc[mi][ni] = __builtin_amdgcn_mfma_f32_16x16x32_bf16(af[mi], bf[ks][ni], acc[mi][ni], 0, 0, 0);
    }
    __syncthreads();
  }
#pragma unroll
  for (int mi = 0; mi < 2; ++mi)
#pragma unroll
    for (int ni = 0; ni < 4; ++ni)
#pragma unroll
      for (int r = 0; r < 4; ++r) {
        int row = m0 + wr + mi * 16 + quad * 4 + r;
        int col = n0 + wc + ni * 16 + cl;
        Cm[(size_t)row * 1024 + col] = acc[mi][ni][r] + bias[col];
      }
}

// ---------- flash attention: R12 exact (best measured: 49.4 us) ----------
__global__ __launch_bounds__(256, 4) void flash_attn(
    const u16* __restrict__ qb, const u16* __restrict__ kf,
    const u16* __restrict__ vf, u16* __restrict__ outp) {
  __shared__ __align__(16) u16 kv[2][16 * 512];    // [buf][K chunks 0-7 | V chunks 8-15]
  const int tid = threadIdx.x, lane = tid & 63, wave = tid >> 6;
  const int quad = lane >> 4, cl = lane & 15;
  const int id = blockIdx.x;
  const int h = (id & 7) | (((id >> 3) & 1) << 3);   // XCD-aware: id%8 = h%8
  const int b = (id >> 4) & 1;
  const int qt = id >> 5;

  const int qrow0 = b * 2048 + qt * 64 + wave * 16;
  short8 bq[2];   // Q as B-operand: B[n=cl][k=quad*8+j]
#pragma unroll
  for (int ks = 0; ks < 2; ++ks)
    bq[ks] = *(const short8*)(qb + (size_t)(qrow0 + cl) * 1024 + h * 64 + ks * 32 + quad * 8);

  const u16* kfb = kf + (size_t)((b * 16 + h) * 32) * 4096;
  const u16* vfb = vf + (size_t)((b * 16 + h) * 32) * 4096;

  auto stage = [&](int kt, int buf) {
#pragma unroll
    for (int i = 0; i < 2; ++i) {
      int c = wave * 2 + i;
      gld_lds16(kfb + (size_t)kt * 4096 + c * 512 + lane * 8, &kv[buf][c * 512]);
      gld_lds16(vfb + (size_t)kt * 4096 + c * 512 + lane * 8, &kv[buf][(8 + c) * 512]);
    }
  };

  f32x4 o_acc[4] = {};   // O^T: row d = nd*16+quad*4+r, col m = cl
  float l_lane = 0.f;

  stage(0, 0);
  __syncthreads();

#pragma unroll 1
  for (int kt = 0; kt < 32; ++kt) {
    const int cur = kt & 1, nxt = cur ^ 1;
    if (kt < 31) stage(kt + 1, nxt);           // DMA overlaps this iter's compute
    const u16* kb = &kv[cur][0];
    const u16* vb = &kv[cur][8 * 512];
    f32x4 st[4] = {};
#pragma unroll
    for (int ks = 0; ks < 2; ++ks)
#pragma unroll
      for (int ni = 0; ni < 4; ++ni) {
        short8 ak = *(const short8*)(kb + (ks * 4 + ni) * 512 + lane * 8);
        st[ni] = __builtin_amdgcn_mfma_f32_16x16x32_bf16(ak, bq[ks], st[ni], 0, 0, 0);
      }
    u32 bp[2][4];
#pragma unroll
    for (int ni = 0; ni < 4; ++ni) {
      float p0 = __builtin_amdgcn_exp2f(st[ni][0]);
      float p1 = __builtin_amdgcn_exp2f(st[ni][1]);
      float p2 = __builtin_amdgcn_exp2f(st[ni][2]);
      float p3 = __builtin_amdgcn_exp2f(st[ni][3]);
      l_lane += (p0 + p1) + (p2 + p3);
      bp[ni >> 1][(ni & 1) * 2 + 0] = pack2bf(p0, p1);
      bp[ni >> 1][(ni & 1) * 2 + 1] = pack2bf(p2, p3);
    }
#pragma unroll
    for (int ks = 0; ks < 2; ++ks) {
      short8 pb;
      *(u32*)&pb     = bp[ks][0];
      ((u32*)&pb)[1] = bp[ks][1];
      ((u32*)&pb)[2] = bp[ks][2];
      ((u32*)&pb)[3] = bp[ks][3];
#pragma unroll
      for (int nd = 0; nd < 4; ++nd) {
        short8 av = *(const short8*)(vb + (ks * 4 + nd) * 512 + lane * 8);
        o_acc[nd] = __builtin_amdgcn_mfma_f32_16x16x32_bf16(av, pb, o_acc[nd], 0, 0, 0);
      }
    }
    __syncthreads();   // waves done reading cur; DMA(nxt) drained
  }
  l_lane += __shfl_xor(l_lane, 16);
  l_lane += __shfl_xor(l_lane, 32);
  float inv = 1.f / l_lane;
  u16* Ow = &kv[0][wave * 16 * 68];
#pragma unroll
  for (int nd = 0; nd < 4; ++nd)
#pragma unroll
    for (int r2 = 0; r2 < 2; ++r2)
      *(u32*)(Ow + cl * 68 + nd * 16 + quad * 4 + r2 * 2) =
          pack2bf(o_acc[nd][r2 * 2] * inv, o_acc[nd][r2 * 2 + 1] * inv);
#pragma unroll
  for (int half = 0; half < 2; ++half) {
    int row = half * 8 + (lane >> 3);
    int d0 = (lane & 7) * 8;
    short8 ov = *(const short8*)(Ow + row * 68 + d0);
    *(short8*)(outp + (size_t)(qrow0 + row) * 1024 + h * 64 + d0) = ov;
  }
}

// ---------- launch ----------
extern "C" void kernel_launch(void* const* d_in, const int* in_sizes, int n_in,
                              void* d_out, int out_size, void* d_ws, size_t ws_size,
                              hipStream_t stream) {
  const float* query   = (const float*)d_in[0];
  const float* context = (const float*)d_in[1];
  const float* Wq  = (const float*)d_in[2];
  const float* bq  = (const float*)d_in[3];
  const float* Wkv = (const float*)d_in[4];
  const float* bkv = (const float*)d_in[5];
  const float* Wo  = (const float*)d_in[6];
  const float* bo  = (const float*)d_in[7];
  float* out = (float*)d_out;

  char* ws = (char*)d_ws;
  size_t off = 0;
  auto alloc = [&](size_t bytes) {
    char* p = ws + off;
    off += (bytes + 255) & ~(size_t)255;
    return p;
  };
  u16* buf0 = (u16*)alloc(4096ull * 1024 * 2);   // Xq -> attn_out
  u16* xcb  = (u16*)alloc(4096ull * 1024 * 2);   // Xc
  u16* WqF  = (u16*)alloc(1024ull * 1024 * 2);   // frag-major weights
  u16* WkvF = (u16*)alloc(2048ull * 1024 * 2);
  u16* WoF  = (u16*)alloc(1024ull * 1024 * 2);
  u16* qb   = (u16*)alloc(4096ull * 1024 * 2);
  u16* kfr  = (u16*)alloc(4ull * 1024 * 1024 * 2);
  u16* vfr  = (u16*)alloc(4ull * 1024 * 1024 * 2);

  const float QSCALE = 0.125f * 1.44269504f;  // 1/sqrt(64) * log2(e)

  pre_kernel<<<12288, dim3(32, 8), 0, stream>>>(query, context, Wq, Wkv, Wo,
                                                buf0, xcb, WqF, WkvF, WoF);
  qkv_gemm<<<768, 256, 0, stream>>>(buf0, xcb, WqF, WkvF, bq, bkv,
                                    qb, kfr, vfr, QSCALE);
  flash_attn<<<1024, 256, 0, stream>>>(qb, kfr, vfr, buf0);
  o_gemm<<<512, 256, 0, stream>>>(buf0, WoF, bo, out);
}